// Round 1
// 538.127 us; speedup vs baseline: 1.0251x; 1.0251x over previous
//
#include <hip/hip_runtime.h>
#include <math.h>

#define N 8192
#define INF 512
#define OUTF 64
#define NEG_SLOPE 0.01f

typedef float f32x4 __attribute__((ext_vector_type(4)));

// ---------------------------------------------------------------------------
// Kernel 1: z = inputs @ W^T + b  (8192x512 @ 512x64), plus
//   zi = sum(a1*z,1), zj = sum(a2*z,1), ztot8 = 8-way-striped column-sum of z.
//
// Core unchanged from the verified 551us version. Only change: the global
// column-sum atomics are striped across 8 slots per feature (blockIdx & 7)
// to cut per-address contention 1024 -> 128 (the 64 hot addresses previously
// spanned only 4 cache lines in one L2 channel).
// ---------------------------------------------------------------------------
__global__ __launch_bounds__(256) void k1_linear(
    const float* __restrict__ inputs, const float* __restrict__ W,
    const float* __restrict__ b, const float* __restrict__ a1,
    const float* __restrict__ a2,
    float* __restrict__ z, float* __restrict__ zi, float* __restrict__ zj,
    float* __restrict__ ztot8)
{
    const int tid = threadIdx.x;
    const int f   = tid & 63;     // output feature
    const int w   = tid >> 6;     // k-quarter
    const int row0 = blockIdx.x * 8;

    __shared__ float part[4][8][64];   // [kquarter][row][feat], lane-stride-1: conflict-free
    __shared__ float ztot_l[64];
    if (tid < 64) ztot_l[tid] = 0.0f;

    float acc[8];
    #pragma unroll
    for (int r = 0; r < 8; ++r) acc[r] = 0.0f;

    const f32x4* wrow = (const f32x4*)(W + (size_t)f * INF + w * 128);
    const f32x4* irow = (const f32x4*)(inputs + (size_t)row0 * INF + w * 128);

    #pragma unroll 4
    for (int k4 = 0; k4 < 32; ++k4) {
        const f32x4 wv = wrow[k4];
        #pragma unroll
        for (int r = 0; r < 8; ++r) {
            const f32x4 iv = irow[(size_t)r * (INF / 4) + k4];
            acc[r] += wv.x * iv.x + wv.y * iv.y + wv.z * iv.z + wv.w * iv.w;
        }
    }
    #pragma unroll
    for (int r = 0; r < 8; ++r) part[w][r][f] = acc[r];
    __syncthreads();

    const float bias = b[f];
    const float a1f = a1[f], a2f = a2[f];
    float colsum = 0.0f;

    #pragma unroll
    for (int p = 0; p < 2; ++p) {
        const int r = w + p * 4;   // 4 waves x 2 passes cover 8 rows; lanes span f=0..63
        const float zv = part[0][r][f] + part[1][r][f] + part[2][r][f] + part[3][r][f] + bias;
        z[(size_t)(row0 + r) * OUTF + f] = zv;
        colsum += zv;
        float s1 = a1f * zv;
        float s2 = a2f * zv;
        #pragma unroll
        for (int m = 32; m > 0; m >>= 1) {
            s1 += __shfl_xor(s1, m, 64);
            s2 += __shfl_xor(s2, m, 64);
        }
        if (f == 0) { zi[row0 + r] = s1; zj[row0 + r] = s2; }
    }

    atomicAdd(&ztot_l[f], colsum);   // 4 adders per slot
    __syncthreads();
    if (tid < 64) atomicAdd(&ztot8[((blockIdx.x & 7) << 6) + tid], ztot_l[tid]);
}

// ---------------------------------------------------------------------------
// Kernel 2: ONE WAVE PER ROW (8192 waves = full chip wave capacity), no LDS,
// no barriers. Scan phase: 32 coalesced f32x4 loads per lane (non-temporal,
// adj is stream-once). Nonzero detection via __ballot -> the extraction loop
// is wave-uniform (mask is the same in every lane): column index j is
// computed from the bit position (no LDS compaction list, no atomics), and
// all 64 lanes gather z[j][lane] (256B coalesced, L2-resident) on the spot.
// Epilogue: closed-form softmax over {0, v, diag} + fused ReLU, full wave.
//   S   = (N-1-c) + c*exp(v) + exp(dv)
//   num = (exp(v)-1)*A + (Ztot - z_i) + exp(dv)*z_i,  A = off-diag neighbor sum
//   out = relu(z_i - num/S)
// ---------------------------------------------------------------------------
__device__ __forceinline__ void proc_comp(float val, int base4, int c,
                                          int i, int lane,
                                          const float* __restrict__ z,
                                          float& acc, float& aii, int& cnt)
{
    unsigned long long m = __ballot(val != 0.0f);
    while (m) {                      // wave-uniform loop: m identical in all lanes
        const int s = __ffsll(m) - 1;
        m &= m - 1;
        const int j = ((base4 + s) << 2) + c;
        if (j == i) {                // uniform branch
            aii = __shfl(val, s, 64);
        } else {
            acc += z[(size_t)j * OUTF + lane];   // coalesced 256B, L2 hit
            ++cnt;
        }
    }
}

__global__ __launch_bounds__(256) void k2_attn(
    const float* __restrict__ adj, const float* __restrict__ eye,
    const float* __restrict__ z, const float* __restrict__ zi,
    const float* __restrict__ zj, const float* __restrict__ ztot8,
    float* __restrict__ out)
{
    const int lane = threadIdx.x & 63;
    const int i    = (blockIdx.x << 2) + (threadIdx.x >> 6);   // one wave per row

    const f32x4* arow = (const f32x4*)(adj + (size_t)i * N);   // 2048 f32x4

    float acc = 0.0f;   // sum over off-diagonal neighbors of z[j][lane]
    float aii = 0.0f;   // adjacency value at the diagonal (0 or 1)
    int   cnt = 0;      // off-diagonal neighbor count (wave-uniform)

    #pragma unroll 1
    for (int it = 0; it < 2048; it += 256) {   // 8 iters, 4 f32x4 per lane in flight
        const f32x4 a0 = __builtin_nontemporal_load(arow + it +   0 + lane);
        const f32x4 a1v = __builtin_nontemporal_load(arow + it +  64 + lane);
        const f32x4 a2v = __builtin_nontemporal_load(arow + it + 128 + lane);
        const f32x4 a3v = __builtin_nontemporal_load(arow + it + 192 + lane);

        proc_comp(a0.x,  it +   0, 0, i, lane, z, acc, aii, cnt);
        proc_comp(a0.y,  it +   0, 1, i, lane, z, acc, aii, cnt);
        proc_comp(a0.z,  it +   0, 2, i, lane, z, acc, aii, cnt);
        proc_comp(a0.w,  it +   0, 3, i, lane, z, acc, aii, cnt);

        proc_comp(a1v.x, it +  64, 0, i, lane, z, acc, aii, cnt);
        proc_comp(a1v.y, it +  64, 1, i, lane, z, acc, aii, cnt);
        proc_comp(a1v.z, it +  64, 2, i, lane, z, acc, aii, cnt);
        proc_comp(a1v.w, it +  64, 3, i, lane, z, acc, aii, cnt);

        proc_comp(a2v.x, it + 128, 0, i, lane, z, acc, aii, cnt);
        proc_comp(a2v.y, it + 128, 1, i, lane, z, acc, aii, cnt);
        proc_comp(a2v.z, it + 128, 2, i, lane, z, acc, aii, cnt);
        proc_comp(a2v.w, it + 128, 3, i, lane, z, acc, aii, cnt);

        proc_comp(a3v.x, it + 192, 0, i, lane, z, acc, aii, cnt);
        proc_comp(a3v.y, it + 192, 1, i, lane, z, acc, aii, cnt);
        proc_comp(a3v.z, it + 192, 2, i, lane, z, acc, aii, cnt);
        proc_comp(a3v.w, it + 192, 3, i, lane, z, acc, aii, cnt);
    }

    // ---- epilogue: closed-form softmax + h = relu(z_i - attn@z) ----
    const float zii = zi[i];
    const float zji = zj[i];
    const float e   = eye[(size_t)i * N + i];

    float ztf = 0.0f;
    #pragma unroll
    for (int s = 0; s < 8; ++s) ztf += ztot8[(s << 6) + lane];

    const float cf = (float)cnt;
    const float v  = (zii > 0.0f) ? zii : NEG_SLOPE * zii;        // lrelu(zi)
    const float dp = aii * zii + aii * e * zji;
    const float dv = (dp > 0.0f) ? dp : NEG_SLOPE * dp;           // lrelu(diag)

    const float expv = expf(v);
    const float expd = expf(dv);
    const float S = (float)(N - 1) - cf + cf * expv + expd;

    const float z_if = z[(size_t)i * OUTF + lane];
    const float num = (expv - 1.0f) * acc + (ztf - z_if) + expd * z_if;
    const float h = z_if - num / S;
    out[(size_t)i * OUTF + lane] = (h > 0.0f) ? h : 0.0f;
}

extern "C" void kernel_launch(void* const* d_in, const int* in_sizes, int n_in,
                              void* d_out, int out_size, void* d_ws, size_t ws_size,
                              hipStream_t stream) {
    const float* inputs = (const float*)d_in[0];
    const float* adj    = (const float*)d_in[1];
    const float* eye    = (const float*)d_in[2];
    const float* W      = (const float*)d_in[3];
    const float* b      = (const float*)d_in[4];
    const float* a1     = (const float*)d_in[5];
    const float* a2     = (const float*)d_in[6];
    float* out = (float*)d_out;

    // workspace layout: z (8192*64) | zi (8192) | zj (8192) | ztot8 (8*64)
    float* z     = (float*)d_ws;
    float* zi    = z + (size_t)N * OUTF;
    float* zj    = zi + N;
    float* ztot8 = zj + N;

    (void)hipMemsetAsync(ztot8, 0, 8 * OUTF * sizeof(float), stream);
    k1_linear<<<N / 8, 256, 0, stream>>>(inputs, W, b, a1, a2, z, zi, zj, ztot8);
    k2_attn<<<N / 4, 256, 0, stream>>>(adj, eye, z, zi, zj, ztot8, out);
}